// Round 1
// baseline (133.063 us; speedup 1.0000x reference)
//
#include <hip/hip_runtime.h>

// Problem constants (from reference):
// B=4, Cin=3, C1=32, C2=Cout=64, IN=32x32, MID=16x16, OUT=8x8, M=512, D=64
// conv: k=4, stride=2, pad=1

// ---------------------------------------------------------------------------
// K1: conv1 JVP  (threads 0..32767)  +  V = lookup @ Wv  (threads 32768..65535)
//   z1  = relu(conv1(x)+b1)                  (B,32,16,16)
//   t1m = (conv1(x)+b1 > 0) ? conv1(x) : 0   (masked tangent, bias removed)
// ---------------------------------------------------------------------------
__global__ __launch_bounds__(256) void k1_conv1_and_V(
    const float* __restrict__ x, const float* __restrict__ w1,
    const float* __restrict__ b1, const float* __restrict__ lookup,
    const float* __restrict__ Wv,
    float* __restrict__ z1, float* __restrict__ t1m, float* __restrict__ V) {
  int t = blockIdx.x * 256 + threadIdx.x;
  if (t < 32768) {
    int b  = t >> 13;          // 32*16*16 = 8192 per sample
    int r  = t & 8191;
    int c1 = r >> 8;           // 16*16 = 256 px
    int p  = r & 255;
    int oh = p >> 4, ow = p & 15;
    float acc = 0.f;
    for (int ci = 0; ci < 3; ++ci) {
      const float* xb = x  + (b * 3 + ci) * 1024;
      const float* wp = w1 + (c1 * 3 + ci) * 16;
      for (int kh = 0; kh < 4; ++kh) {
        int ih = oh * 2 - 1 + kh;
        if ((unsigned)ih >= 32u) continue;
        for (int kw = 0; kw < 4; ++kw) {
          int iw = ow * 2 - 1 + kw;
          if ((unsigned)iw >= 32u) continue;
          acc += xb[ih * 32 + iw] * wp[kh * 4 + kw];
        }
      }
    }
    float pre = acc + b1[c1];
    bool on = pre > 0.f;
    z1[t]  = on ? pre : 0.f;
    t1m[t] = on ? acc : 0.f;   // (pre - b1) * mask
  } else {
    int u = t - 32768;
    int m = u >> 6, d = u & 63;
    const float* lp = lookup + m * 64;
    float acc = 0.f;
    for (int k = 0; k < 64; ++k) acc += lp[k] * Wv[k * 64 + d];
    V[u] = acc;
  }
}

// ---------------------------------------------------------------------------
// K2: conv2 JVP -> tokens[b][c2][p] = (conv2(z1)+b2 > 0) ? conv2(t1m) : 0
// ---------------------------------------------------------------------------
__global__ __launch_bounds__(256) void k2_conv2_tokens(
    const float* __restrict__ z1, const float* __restrict__ t1m,
    const float* __restrict__ w2, const float* __restrict__ b2,
    float* __restrict__ tokens) {
  int t  = blockIdx.x * 256 + threadIdx.x;  // 16384 total
  int b  = t >> 12;
  int r  = t & 4095;
  int c2 = r >> 6;
  int p  = r & 63;
  int oh = p >> 3, ow = p & 7;
  float accz = 0.f, acct = 0.f;
  for (int c1 = 0; c1 < 32; ++c1) {
    const float* zb = z1  + (b * 32 + c1) * 256;
    const float* tb = t1m + (b * 32 + c1) * 256;
    const float* wp = w2  + (c2 * 32 + c1) * 16;
    for (int kh = 0; kh < 4; ++kh) {
      int ih = oh * 2 - 1 + kh;
      if ((unsigned)ih >= 16u) continue;
      for (int kw = 0; kw < 4; ++kw) {
        int iw = ow * 2 - 1 + kw;
        if ((unsigned)iw >= 16u) continue;
        float wv  = wp[kh * 4 + kw];
        int   idx = ih * 16 + iw;
        accz += zb[idx] * wv;
        acct += tb[idx] * wv;
      }
    }
  }
  float pre = accz + b2[c2];
  tokens[t] = (pre > 0.f) ? acct : 0.f;  // layout [b][c2][p] == flat t
}

// ---------------------------------------------------------------------------
// K3: Hopfield retrieval, one block per (b, n) token. 256 threads.
//   scores -> softmax(512) -> @V -> @Wo -> out[b][d'][n]
// ---------------------------------------------------------------------------
__global__ __launch_bounds__(256) void k3_hopfield(
    const float* __restrict__ tokens, const float* __restrict__ lookup,
    const float* __restrict__ V, const float* __restrict__ Wo,
    float* __restrict__ out) {
  __shared__ float tok[64];
  __shared__ float sc[512];
  __shared__ float red[256];
  __shared__ float part[4][64];
  __shared__ float yv[64];
  int tid = threadIdx.x;
  int b = blockIdx.x >> 6, n = blockIdx.x & 63;

  if (tid < 64) tok[tid] = tokens[b * 4096 + tid * 64 + n];
  __syncthreads();

  // scores vs all 512 memory rows (beta = 1/sqrt(64) = 0.125)
  for (int m = tid; m < 512; m += 256) {
    const float* lp = lookup + m * 64;
    float s = 0.f;
    for (int d = 0; d < 64; ++d) s += tok[d] * lp[d];
    sc[m] = s * 0.125f;
  }
  __syncthreads();

  // block max over 512
  red[tid] = fmaxf(sc[tid], sc[tid + 256]);
  __syncthreads();
  for (int s = 128; s > 0; s >>= 1) {
    if (tid < s) red[tid] = fmaxf(red[tid], red[tid + s]);
    __syncthreads();
  }
  float maxv = red[0];
  __syncthreads();

  // exp + block sum
  float e0 = expf(sc[tid] - maxv), e1 = expf(sc[tid + 256] - maxv);
  sc[tid] = e0; sc[tid + 256] = e1;
  red[tid] = e0 + e1;
  __syncthreads();
  for (int s = 128; s > 0; s >>= 1) {
    if (tid < s) red[tid] += red[tid + s];
    __syncthreads();
  }
  float inv = 1.f / red[0];

  // y[d] = (sum_m sc[m] * V[m][d]) * inv   — 4 m-groups x 64 d
  int g = tid >> 6, d = tid & 63;
  float acc = 0.f;
  const float* vp = V + g * 128 * 64 + d;
  for (int m = 0; m < 128; ++m) acc += sc[g * 128 + m] * vp[m * 64];
  part[g][d] = acc;
  __syncthreads();
  if (tid < 64)
    yv[tid] = (part[0][tid] + part[1][tid] + part[2][tid] + part[3][tid]) * inv;
  __syncthreads();

  // out[b][d'][n] = sum_d yv[d] * Wo[d][d']
  if (tid < 64) {
    float o = 0.f;
    for (int d2 = 0; d2 < 64; ++d2) o += yv[d2] * Wo[d2 * 64 + tid];
    out[b * 4096 + tid * 64 + n] = o;
  }
}

extern "C" void kernel_launch(void* const* d_in, const int* in_sizes, int n_in,
                              void* d_out, int out_size, void* d_ws, size_t ws_size,
                              hipStream_t stream) {
  const float* x      = (const float*)d_in[0];
  const float* w1     = (const float*)d_in[1];
  const float* b1     = (const float*)d_in[2];
  const float* w2     = (const float*)d_in[3];
  const float* b2     = (const float*)d_in[4];
  const float* lookup = (const float*)d_in[5];
  const float* Wv     = (const float*)d_in[6];
  const float* Wo     = (const float*)d_in[7];

  float* ws     = (float*)d_ws;
  float* z1     = ws;            // 32768 floats (B,32,16,16)
  float* t1m    = ws + 32768;    // 32768
  float* V      = ws + 65536;    // 32768 (512,64)
  float* tokens = ws + 98304;    // 16384 (B,64ch,64px)
  float* out    = (float*)d_out; // 16384 (B,64,8,8)

  k1_conv1_and_V<<<256, 256, 0, stream>>>(x, w1, b1, lookup, Wv, z1, t1m, V);
  k2_conv2_tokens<<<64, 256, 0, stream>>>(z1, t1m, w2, b2, tokens);
  k3_hopfield<<<256, 256, 0, stream>>>(tokens, lookup, V, Wo, out);
}

// Round 2
// 95.012 us; speedup vs baseline: 1.4005x; 1.4005x over previous
//
#include <hip/hip_runtime.h>

// B=4, Cin=3, C1=32, C2=64, IN=32x32, MID=16x16, OUT=8x8, M=512, D=64
// conv k=4 s=2 p=1.  JVP identity: J.x = D2 W2 D1 W1 x  (piecewise-linear net),
// so tokens = (pre2>0) * conv2( (pre1>0) * (pre1 - b1) ).

// ---------------------------------------------------------------------------
// K1: 256 blocks. blk<128: conv1 JVP for (b,c1) = (blk>>5, blk&31), one thread
// per 16x16 output pixel, x[b] staged in LDS. blk>=128: V = lookup @ Wv.
// ---------------------------------------------------------------------------
__global__ __launch_bounds__(256) void k1_conv1_and_V(
    const float* __restrict__ x, const float* __restrict__ w1,
    const float* __restrict__ b1, const float* __restrict__ lookup,
    const float* __restrict__ Wv,
    float* __restrict__ z1, float* __restrict__ t1m, float* __restrict__ V) {
  int blk = blockIdx.x, tid = threadIdx.x;
  if (blk < 128) {
    __shared__ float xs[3072];  // 3 planes of 32x32
    int b = blk >> 5, c1 = blk & 31;
    const float4* xsrc = (const float4*)(x + b * 3072);
    float4* xdst = (float4*)xs;
#pragma unroll
    for (int i = 0; i < 3; ++i) xdst[tid + i * 256] = xsrc[tid + i * 256];
    __syncthreads();
    int oh = tid >> 4, ow = tid & 15;
    int iw0 = ow * 2 - 1;
    float acc = 0.f;
#pragma unroll
    for (int ci = 0; ci < 3; ++ci) {
      const float* xp = xs + ci * 1024;
      const float4* wp = (const float4*)(w1 + (c1 * 3 + ci) * 16);
      float4 wr0 = wp[0], wr1 = wp[1], wr2 = wp[2], wr3 = wp[3];
#pragma unroll
      for (int kh = 0; kh < 4; ++kh) {
        int ih = oh * 2 - 1 + kh;
        if ((unsigned)ih < 32u) {
          float4 wk = (kh == 0) ? wr0 : (kh == 1) ? wr1 : (kh == 2) ? wr2 : wr3;
          const float* row = xp + ih * 32;
          if (iw0 >= 0)      acc += row[iw0]     * wk.x;
                             acc += row[iw0 + 1] * wk.y;
                             acc += row[iw0 + 2] * wk.z;
          if (iw0 + 3 < 32)  acc += row[iw0 + 3] * wk.w;
        }
      }
    }
    float pre = acc + b1[c1];
    bool on = pre > 0.f;
    int o = ((b * 32 + c1) << 8) + tid;
    z1[o]  = on ? pre : 0.f;
    t1m[o] = on ? acc : 0.f;   // mask * (pre - b1)
  } else {
    int u = ((blk - 128) << 8) + tid;   // 0..32767
    int m = u >> 6, d = u & 63;
    const float* lp = lookup + m * 64;
    float acc = 0.f;
#pragma unroll
    for (int k = 0; k < 64; ++k) acc += lp[k] * Wv[k * 64 + d];
    V[u] = acc;
  }
}

// ---------------------------------------------------------------------------
// K2: 256 blocks = (b, c2). z1/t1m for sample b staged interleaved in LDS
// (float2 = (z,t), 64 KB exactly), XOR-swizzled by (c1 & 15) for bank spread.
// Threads: quad (g=tid&3) splits the 32-c1 reduction, p=tid>>2 is the pixel.
// ---------------------------------------------------------------------------
__global__ __launch_bounds__(256) void k2_conv2_tokens(
    const float* __restrict__ z1, const float* __restrict__ t1m,
    const float* __restrict__ w2, const float* __restrict__ b2,
    float* __restrict__ tokens) {
  __shared__ float2 ZT[8192];   // [c1][idx^s]: 32 planes x 256 slots
  int tid = threadIdx.x;
  int b = blockIdx.x >> 6, c2 = blockIdx.x & 63;

  const float4* z4 = (const float4*)(z1 + (b << 13));
  const float4* t4 = (const float4*)(t1m + (b << 13));
#pragma unroll
  for (int i = 0; i < 8; ++i) {
    int f = tid + (i << 8);            // float4 index 0..2047 (4 elements each)
    float4 zv = z4[f], tv = t4[f];
    int c1 = f >> 6;
    int i0 = (f & 63) << 2;            // within-plane element base (mult of 4)
    int s = c1 & 15;
    int perm = s & 3;
    float2 e0 = {zv.x, tv.x}, e1 = {zv.y, tv.y}, e2 = {zv.z, tv.z}, e3 = {zv.w, tv.w};
    // dst[j] must hold element (j ^ perm): XOR-perm = two conditional swap stages
    if (perm & 1) { float2 t = e0; e0 = e1; e1 = t; t = e2; e2 = e3; e3 = t; }
    if (perm & 2) { float2 t = e0; e0 = e2; e2 = t; t = e1; e1 = e3; e3 = t; }
    float2* dst = &ZT[(c1 << 8) + (i0 ^ (s & 12))];
    dst[0] = e0; dst[1] = e1; dst[2] = e2; dst[3] = e3;
  }
  __syncthreads();

  int g = tid & 3, p = tid >> 2;
  int oh = p >> 3, ow = p & 7;
  int iw0 = ow * 2 - 1;
  float accz = 0.f, acct = 0.f;
#pragma unroll
  for (int j = 0; j < 8; ++j) {
    int c1 = g + (j << 2);
    int s = c1 & 15;
    const float2* zp = &ZT[c1 << 8];
    const float4* wp = (const float4*)(w2 + ((c2 * 32 + c1) << 4));
    float4 wr0 = wp[0], wr1 = wp[1], wr2 = wp[2], wr3 = wp[3];
#pragma unroll
    for (int kh = 0; kh < 4; ++kh) {
      int ih = oh * 2 - 1 + kh;
      if ((unsigned)ih < 16u) {
        float4 wk = (kh == 0) ? wr0 : (kh == 1) ? wr1 : (kh == 2) ? wr2 : wr3;
        int base = ih << 4;
        if (iw0 >= 0) { float2 v = zp[(base + iw0) ^ s];     accz += v.x * wk.x; acct += v.y * wk.x; }
        {               float2 v = zp[(base + iw0 + 1) ^ s]; accz += v.x * wk.y; acct += v.y * wk.y; }
        {               float2 v = zp[(base + iw0 + 2) ^ s]; accz += v.x * wk.z; acct += v.y * wk.z; }
        if (iw0 + 3 < 16) { float2 v = zp[(base + iw0 + 3) ^ s]; accz += v.x * wk.w; acct += v.y * wk.w; }
      }
    }
  }
  accz += __shfl_xor(accz, 1); acct += __shfl_xor(acct, 1);
  accz += __shfl_xor(accz, 2); acct += __shfl_xor(acct, 2);
  if (g == 0) {
    float pre = accz + b2[c2];
    tokens[(b << 12) + (c2 << 6) + p] = (pre > 0.f) ? acct : 0.f;
  }
}

// ---------------------------------------------------------------------------
// K3: 256 blocks = (b, n). Quad-per-row scores (registered token fragments),
// shuffle max/sum, __expf, grouped V/Wo matvecs. 6 barriers total.
// ---------------------------------------------------------------------------
__global__ __launch_bounds__(256) void k3_hopfield(
    const float* __restrict__ tokens, const float* __restrict__ lookup,
    const float* __restrict__ V, const float* __restrict__ Wo,
    float* __restrict__ out) {
  __shared__ float tok[64];
  __shared__ float prob[512];
  __shared__ float redbuf[8];
  __shared__ float part[4][64];
  __shared__ float yv[64];
  int tid = threadIdx.x;
  int b = blockIdx.x >> 6, n = blockIdx.x & 63;

  if (tid < 64) tok[tid] = tokens[(b << 12) + (tid << 6) + n];
  __syncthreads();

  int q = tid >> 2, l = tid & 3, w = tid >> 6;
  const float4* tk4 = (const float4*)tok;
  float4 ta = tk4[(l << 2) + 0], tb = tk4[(l << 2) + 1],
         tc = tk4[(l << 2) + 2], td = tk4[(l << 2) + 3];
  float sc[8];
#pragma unroll
  for (int i = 0; i < 8; ++i) {
    int m = q + (i << 6);
    const float4* lp = (const float4*)(lookup + (m << 6)) + (l << 2);
    float4 A = lp[0], B = lp[1], C = lp[2], D = lp[3];
    float s = A.x * ta.x + A.y * ta.y + A.z * ta.z + A.w * ta.w
            + B.x * tb.x + B.y * tb.y + B.z * tb.z + B.w * tb.w
            + C.x * tc.x + C.y * tc.y + C.z * tc.z + C.w * tc.w
            + D.x * td.x + D.y * td.y + D.z * td.z + D.w * td.w;
    s += __shfl_xor(s, 1);
    s += __shfl_xor(s, 2);
    sc[i] = s * 0.125f;           // beta = 1/sqrt(64)
  }
  // global max
  float mx = sc[0];
#pragma unroll
  for (int i = 1; i < 8; ++i) mx = fmaxf(mx, sc[i]);
  mx = fmaxf(mx, __shfl_xor(mx, 4));
  mx = fmaxf(mx, __shfl_xor(mx, 8));
  mx = fmaxf(mx, __shfl_xor(mx, 16));
  mx = fmaxf(mx, __shfl_xor(mx, 32));
  if ((tid & 63) == 0) redbuf[w] = mx;
  __syncthreads();
  mx = fmaxf(fmaxf(redbuf[0], redbuf[1]), fmaxf(redbuf[2], redbuf[3]));

  // exp + global sum; store probs
  float e[8];
  float sum = 0.f;
#pragma unroll
  for (int i = 0; i < 8; ++i) { e[i] = __expf(sc[i] - mx); sum += e[i]; }
  if (l != 0) sum = 0.f;          // quad lanes duplicate rows
  sum += __shfl_xor(sum, 1);
  sum += __shfl_xor(sum, 2);
  sum += __shfl_xor(sum, 4);
  sum += __shfl_xor(sum, 8);
  sum += __shfl_xor(sum, 16);
  sum += __shfl_xor(sum, 32);
  if ((tid & 63) == 0) redbuf[4 + w] = sum;
  if (l == 0) {
#pragma unroll
    for (int i = 0; i < 8; ++i) prob[q + (i << 6)] = e[i];
  }
  __syncthreads();
  float inv = 1.f / (redbuf[4] + redbuf[5] + redbuf[6] + redbuf[7]);

  // y[d] = inv * sum_m prob[m] V[m][d]; wave w handles 128 m-rows
  int d = tid & 63;
  float acc = 0.f;
  const float* vp = V + (w << 7) * 64 + d;
#pragma unroll 4
  for (int m = 0; m < 128; ++m) acc += prob[(w << 7) + m] * vp[m << 6];
  part[w][d] = acc;
  __syncthreads();
  if (tid < 64)
    yv[tid] = (part[0][tid] + part[1][tid] + part[2][tid] + part[3][tid]) * inv;
  __syncthreads();

  // out[d'] = sum_d2 yv[d2] Wo[d2][d']; wave w handles d2 in [w*16, w*16+16)
  float po = 0.f;
#pragma unroll
  for (int k = 0; k < 16; ++k) {
    int d2 = (w << 4) + k;
    po += yv[d2] * Wo[(d2 << 6) + d];
  }
  __syncthreads();
  part[w][d] = po;
  __syncthreads();
  if (tid < 64)
    out[(b << 12) + (tid << 6) + n] =
        part[0][tid] + part[1][tid] + part[2][tid] + part[3][tid];
}

extern "C" void kernel_launch(void* const* d_in, const int* in_sizes, int n_in,
                              void* d_out, int out_size, void* d_ws, size_t ws_size,
                              hipStream_t stream) {
  const float* x      = (const float*)d_in[0];
  const float* w1     = (const float*)d_in[1];
  const float* b1     = (const float*)d_in[2];
  const float* w2     = (const float*)d_in[3];
  const float* b2     = (const float*)d_in[4];
  const float* lookup = (const float*)d_in[5];
  const float* Wv     = (const float*)d_in[6];
  const float* Wo     = (const float*)d_in[7];

  float* ws     = (float*)d_ws;
  float* z1     = ws;            // 32768 floats (B,32,16,16)
  float* t1m    = ws + 32768;    // 32768
  float* V      = ws + 65536;    // 32768 (512,64)
  float* tokens = ws + 98304;    // 16384 (B,64,64)
  float* out    = (float*)d_out; // 16384 (B,64,8,8)

  k1_conv1_and_V<<<256, 256, 0, stream>>>(x, w1, b1, lookup, Wv, z1, t1m, V);
  k2_conv2_tokens<<<256, 256, 0, stream>>>(z1, t1m, w2, b2, tokens);
  k3_hopfield<<<256, 256, 0, stream>>>(tokens, lookup, V, Wo, out);
}

// Round 3
// 82.067 us; speedup vs baseline: 1.6214x; 1.1577x over previous
//
#include <hip/hip_runtime.h>

// B=4, Cin=3, C1=32, C2=64, IN=32x32, MID=16x16, OUT=8x8, M=512, D=64
// conv k=4 s=2 p=1.
// JVP identity (piecewise-linear net): J.x = D2 W2 D1 W1 x, so
//   tokens[b,:,n] = (pre2>0) * conv2( (pre1>0) * (pre1 - b1) )  at pixel n.
// Hopfield tail reassociated: out = ((softmax(tok.lookup^T/8) @ lookup) @ Wv) @ Wo
// -> no V precompute, no inter-block dependency. ONE kernel, 256 independent
// blocks = (b, n) output tokens, zero workspace.

__global__ __launch_bounds__(256) void fused_all(
    const float* __restrict__ x, const float* __restrict__ w1,
    const float* __restrict__ b1, const float* __restrict__ w2,
    const float* __restrict__ b2, const float* __restrict__ lookup,
    const float* __restrict__ Wv, const float* __restrict__ Wo,
    float* __restrict__ out) {
  __shared__ float xs[3072];       // x[b]: 3 planes 32x32
  __shared__ float ws1[32 * 49];   // w1 padded: [c1]*49 + ci*16 + r*4 + s
  __shared__ float2 zt[512];       // [k=kh*4+kw][c1]: (z1, t1m) on the 4x4 mid window
  __shared__ float4 tok4[16];      // token vector (64 channels)
  __shared__ float prob[512];
  __shared__ float redbuf[8];
  __shared__ float part[4][64];
  __shared__ float vec[64];        // reused: u = assoc@lookup, then y1 = u@Wv

  int tid = threadIdx.x;
  int b = blockIdx.x >> 6, n = blockIdx.x & 63;
  int Oh = n >> 3, Ow = n & 7;

  // ---- stage x[b] (float4) and w1 (stride-49 pad: bank-conflict-free) ----
  {
    const float4* xsrc = (const float4*)(x + b * 3072);
    float4* xdst = (float4*)xs;
#pragma unroll
    for (int i = 0; i < 3; ++i) xdst[tid + i * 256] = xsrc[tid + i * 256];
#pragma unroll
    for (int i = 0; i < 6; ++i) {
      int idx = tid + (i << 8);            // 0..1535 exactly
      int c1 = idx / 48, r = idx - c1 * 48;
      ws1[c1 * 49 + r] = w1[idx];
    }
  }
  __syncthreads();

  // ---- conv1 JVP on the 4x4 mid-window feeding output pixel (Oh,Ow) ----
  // 512 tasks = (c1, k); zero for out-of-range mid pixels (== zero padding).
#pragma unroll
  for (int i = 0; i < 2; ++i) {
    int u = tid + (i << 8);
    int c1 = u & 31, k = u >> 5;           // k in [0,16)
    int kh = k >> 2, kw = k & 3;
    int mh = 2 * Oh - 1 + kh, mw = 2 * Ow - 1 + kw;
    float z = 0.f, t = 0.f;
    if (((unsigned)mh < 16u) && ((unsigned)mw < 16u)) {
      float acc = 0.f;
      int ih0 = 2 * mh - 1, iw0 = 2 * mw - 1;
#pragma unroll
      for (int ci = 0; ci < 3; ++ci) {
        const float* xp = xs + ci * 1024;
        const float* wp = ws1 + c1 * 49 + ci * 16;
#pragma unroll
        for (int r = 0; r < 4; ++r) {
          int ih = ih0 + r;
          if ((unsigned)ih < 32u) {
            const float* row = xp + ih * 32;
            if (iw0 >= 0)     acc += row[iw0]     * wp[r * 4 + 0];
                              acc += row[iw0 + 1] * wp[r * 4 + 1];
                              acc += row[iw0 + 2] * wp[r * 4 + 2];
            if (iw0 + 3 < 32) acc += row[iw0 + 3] * wp[r * 4 + 3];
          }
        }
      }
      float pre = acc + b1[c1];
      if (pre > 0.f) { z = pre; t = acc; }   // t = mask * (pre - b1)
    }
    zt[k * 32 + c1] = make_float2(z, t);
  }
  __syncthreads();

  // ---- conv2 JVP -> token[c2]; quad-split over c1 ----
  {
    int c2 = tid >> 2, g = tid & 3;
    float accz = 0.f, acct = 0.f;
#pragma unroll
    for (int j = 0; j < 8; ++j) {
      int c1 = g + (j << 2);
      const float4* wp = (const float4*)(w2 + ((c2 * 32 + c1) << 4));
      float wk[16];
      *(float4*)(wk + 0) = wp[0]; *(float4*)(wk + 4) = wp[1];
      *(float4*)(wk + 8) = wp[2]; *(float4*)(wk + 12) = wp[3];
      const float2* zp = zt + c1;
#pragma unroll
      for (int k = 0; k < 16; ++k) {
        float2 v = zp[k << 5];
        accz += v.x * wk[k];
        acct += v.y * wk[k];
      }
    }
    accz += __shfl_xor(accz, 1); acct += __shfl_xor(acct, 1);
    accz += __shfl_xor(accz, 2); acct += __shfl_xor(acct, 2);
    if (g == 0) {
      float pre = accz + b2[c2];
      ((float*)tok4)[c2] = (pre > 0.f) ? acct : 0.f;
    }
  }
  __syncthreads();

  // ---- scores vs 512 lookup rows; quad-per-row, beta = 0.125 ----
  int q = tid >> 2, l = tid & 3, w = tid >> 6;
  float4 ta = tok4[(l << 2) + 0], tb = tok4[(l << 2) + 1],
         tc = tok4[(l << 2) + 2], td = tok4[(l << 2) + 3];
  float sc[8];
#pragma unroll
  for (int i = 0; i < 8; ++i) {
    int m = q + (i << 6);
    const float4* lp = (const float4*)(lookup + (m << 6)) + (l << 2);
    float4 A = lp[0], B = lp[1], C = lp[2], D = lp[3];
    float s = A.x * ta.x + A.y * ta.y + A.z * ta.z + A.w * ta.w
            + B.x * tb.x + B.y * tb.y + B.z * tb.z + B.w * tb.w
            + C.x * tc.x + C.y * tc.y + C.z * tc.z + C.w * tc.w
            + D.x * td.x + D.y * td.y + D.z * td.z + D.w * td.w;
    s += __shfl_xor(s, 1);
    s += __shfl_xor(s, 2);
    sc[i] = s * 0.125f;
  }
  float mx = sc[0];
#pragma unroll
  for (int i = 1; i < 8; ++i) mx = fmaxf(mx, sc[i]);
  mx = fmaxf(mx, __shfl_xor(mx, 4));
  mx = fmaxf(mx, __shfl_xor(mx, 8));
  mx = fmaxf(mx, __shfl_xor(mx, 16));
  mx = fmaxf(mx, __shfl_xor(mx, 32));
  if ((tid & 63) == 0) redbuf[w] = mx;
  __syncthreads();
  mx = fmaxf(fmaxf(redbuf[0], redbuf[1]), fmaxf(redbuf[2], redbuf[3]));

  float e[8];
  float sum = 0.f;
#pragma unroll
  for (int i = 0; i < 8; ++i) { e[i] = __expf(sc[i] - mx); sum += e[i]; }
  if (l != 0) sum = 0.f;                   // quad lanes duplicate rows
  sum += __shfl_xor(sum, 1);
  sum += __shfl_xor(sum, 2);
  sum += __shfl_xor(sum, 4);
  sum += __shfl_xor(sum, 8);
  sum += __shfl_xor(sum, 16);
  sum += __shfl_xor(sum, 32);
  if ((tid & 63) == 0) redbuf[4 + w] = sum;
  if (l == 0) {
#pragma unroll
    for (int i = 0; i < 8; ++i) prob[q + (i << 6)] = e[i];
  }
  __syncthreads();
  float inv = 1.f / (redbuf[4] + redbuf[5] + redbuf[6] + redbuf[7]);

  // ---- u[d] = inv * sum_m prob[m] * lookup[m][d]; wave w owns 128 m-rows ----
  int d = tid & 63;
  float acc = 0.f;
  const float* lp = lookup + ((w << 7) << 6) + d;
#pragma unroll 4
  for (int m = 0; m < 128; ++m) acc += prob[(w << 7) + m] * lp[m << 6];
  part[w][d] = acc;
  __syncthreads();
  if (tid < 64)
    vec[tid] = (part[0][tid] + part[1][tid] + part[2][tid] + part[3][tid]) * inv;
  __syncthreads();

  // ---- y1 = u @ Wv ----
  float po = 0.f;
#pragma unroll
  for (int k = 0; k < 16; ++k) {
    int d2 = (w << 4) + k;
    po += vec[d2] * Wv[(d2 << 6) + d];
  }
  __syncthreads();
  part[w][d] = po;
  __syncthreads();
  if (tid < 64)
    vec[tid] = part[0][tid] + part[1][tid] + part[2][tid] + part[3][tid];
  __syncthreads();

  // ---- y2 = y1 @ Wo -> out[b][d'][n] ----
  po = 0.f;
#pragma unroll
  for (int k = 0; k < 16; ++k) {
    int d2 = (w << 4) + k;
    po += vec[d2] * Wo[(d2 << 6) + d];
  }
  __syncthreads();
  part[w][d] = po;
  __syncthreads();
  if (tid < 64)
    out[(b << 12) + (tid << 6) + n] =
        part[0][tid] + part[1][tid] + part[2][tid] + part[3][tid];
}

extern "C" void kernel_launch(void* const* d_in, const int* in_sizes, int n_in,
                              void* d_out, int out_size, void* d_ws, size_t ws_size,
                              hipStream_t stream) {
  const float* x      = (const float*)d_in[0];
  const float* w1     = (const float*)d_in[1];
  const float* b1     = (const float*)d_in[2];
  const float* w2     = (const float*)d_in[3];
  const float* b2     = (const float*)d_in[4];
  const float* lookup = (const float*)d_in[5];
  const float* Wv     = (const float*)d_in[6];
  const float* Wo     = (const float*)d_in[7];
  float* out = (float*)d_out;

  fused_all<<<256, 256, 0, stream>>>(x, w1, b1, w2, b2, lookup, Wv, Wo, out);
}